// Round 9
// baseline (158.460 us; speedup 1.0000x reference)
//
#include <hip/hip_runtime.h>
#include <cstddef>
#include <cstdint>

// Problem constants (B,N,H) = (8,256,64)
constexpr int Bv = 8, Nv = 256, Hv = 64;
constexpr int ROWS = Bv * Nv;            // 2048
constexpr float INV_EDGE_CNT = 1.0f / (8.0f * 256.0f * 256.0f);
constexpr float INV_NODE_CNT = 1.0f / 2048.0f;
constexpr float EPSBN = 1e-5f;

// ws layout (float offsets)
constexpr size_t WS_VXE  = 0;          // [2048*64] PACKED [b][jt][t][lane][4]
constexpr size_t WS_VXN  = 131072;     // [2048*64] PACKED
constexpr size_t WS_UX   = 262144;     // [2048*64] linear [r][c]
constexpr size_t WS_AGG  = 393216;     // [2048*64] linear [r][c]
constexpr size_t WS_ESUM = 524288;     // [64]  k_node writes edge-BN scale
constexpr size_t WS_ESQ  = 524352;     // [64]  k_node writes edge-BN shift
constexpr size_t WS_PART = 524416;     // [2048][128] per-block partial s|q

typedef __bf16 bf16x8 __attribute__((ext_vector_type(8)));
typedef float  f32x4  __attribute__((ext_vector_type(4)));

__device__ __forceinline__ float4 ld4(const float* p) {
  return *reinterpret_cast<const float4*>(p);
}

__device__ __forceinline__ bf16x8 cvt8(float4 a, float4 b) {
  bf16x8 r;
  r[0] = (__bf16)a.x; r[1] = (__bf16)a.y; r[2] = (__bf16)a.z; r[3] = (__bf16)a.w;
  r[4] = (__bf16)b.x; r[5] = (__bf16)b.y; r[6] = (__bf16)b.z; r[7] = (__bf16)b.w;
  return r;
}

// A-fragment (one 16-j MFMA tile) direct global->regs; per-lane private.
__device__ __forceinline__ void loadA(float4 A[4], const float* eTile,
                                      int j0, int r16, int g) {
  const float* ep = eTile + (size_t)(j0 + r16) * 64 + 8 * g;
  A[0] = ld4(ep);      A[1] = ld4(ep + 4);
  A[2] = ld4(ep + 32); A[3] = ld4(ep + 36);
}

#define DOT4(acc, a, b) \
  acc = fmaf((a).x, (b).x, fmaf((a).y, (b).y, fmaf((a).z, (b).z, fmaf((a).w, (b).w, acc))))

// ---------------------------------------------------------------------------
// Linears: Vxe / Vxn written PACKED for the edge-kernel epilogue lane order;
// Ux written linear for k_node. Thread = (row, t, g) -> 4 channels.
__global__ __launch_bounds__(256) void k_lin(
    const float* __restrict__ x,
    const float* __restrict__ VeW, const float* __restrict__ Veb,
    const float* __restrict__ UnW, const float* __restrict__ Unb,
    const float* __restrict__ VnW, const float* __restrict__ Vnb,
    float* __restrict__ ws)
{
  const int idx = blockIdx.x * 256 + threadIdx.x;   // 32768 total
  const int r  = idx >> 4;           // row 0..2047
  const int tg = idx & 15;
  const int t  = tg >> 2, g = tg & 3;
  const int c0 = t * 16 + g * 4;

  const float4* x4 = (const float4*)(x + (size_t)r * 64);
  float a1[4] = {}, a2[4] = {}, a3[4] = {};
#pragma unroll
  for (int h = 0; h < 16; ++h) {
    float4 xv = x4[h];
#pragma unroll
    for (int cc = 0; cc < 4; ++cc) {
      float4 w1 = ld4(VeW + (size_t)(c0 + cc) * 64 + h * 4); DOT4(a1[cc], xv, w1);
      float4 w2 = ld4(UnW + (size_t)(c0 + cc) * 64 + h * 4); DOT4(a2[cc], xv, w2);
      float4 w3 = ld4(VnW + (size_t)(c0 + cc) * 64 + h * 4); DOT4(a3[cc], xv, w3);
    }
  }

  const int b = r >> 8, jt = (r >> 4) & 15, r16 = r & 15;
  const size_t pidx = ((size_t)((b * 16 + jt) * 4 + t)) * 256 + (g * 16 + r16) * 4;
  *(float4*)(&ws[WS_VXE + pidx]) =
      make_float4(a1[0] + Veb[c0], a1[1] + Veb[c0 + 1], a1[2] + Veb[c0 + 2], a1[3] + Veb[c0 + 3]);
  *(float4*)(&ws[WS_VXN + pidx]) =
      make_float4(a3[0] + Vnb[c0], a3[1] + Vnb[c0 + 1], a3[2] + Vnb[c0 + 2], a3[3] + Vnb[c0 + 3]);
  *(float4*)(&ws[WS_UX + (size_t)r * 64 + c0]) =
      make_float4(a2[0] + Unb[c0], a2[1] + Unb[c0 + 1], a2[2] + Unb[c0 + 2], a2[3] + Unb[c0 + 3]);
}

// ---------------------------------------------------------------------------
// Pass A: e_tmp = e@UeW^T + b + Vxe_i + Vxe_j via MFMA(W,e); wave w owns
// j-rows [64w,64w+64). NO LDS in the loop: A-fragments are per-lane private,
// loaded global->reg with 2-tile prefetch (pure register dataflow; precise
// compiler-counted waits). NO global atomics: per-block partials to WS_PART.
__global__ __launch_bounds__(256, 3) void k_edgeA(
    const float* __restrict__ e,
    const float* __restrict__ UeW, const float* __restrict__ Ueb,
    float* __restrict__ ws)
{
  __shared__ float redL[3 * 256];    // 3KB: cross-wave reduce only

  const int tid  = threadIdx.x;
  const int lane = tid & 63;
  const int w    = tid >> 6;
  const int bi   = blockIdx.x;
  const int b    = bi >> 8;
  const int r16  = lane & 15;
  const int g    = lane >> 4;

  const float* eTile = e + (size_t)bi * (Nv * Hv);
  const float* VXEP = ws + WS_VXE;
  const float* VXNP = ws + WS_VXN;

  // W fragments (A-operand of mfma(W,e)) direct from global (L2-hot 16KB)
  bf16x8 wF0[4], wF1[4];
#pragma unroll
  for (int t = 0; t < 4; ++t) {
    const float* wrow = UeW + (size_t)(t * 16 + r16) * 64 + 8 * g;
    wF0[t] = cvt8(ld4(wrow),      ld4(wrow + 4));
    wF1[t] = cvt8(ld4(wrow + 32), ld4(wrow + 36));
  }

  // uv = Ueb + Vxe_i (folded once; per-lane channels c = 16t+4g+r)
  const int jti = (bi >> 4) & 15, r16i = bi & 15;
  float uv[4][4];
#pragma unroll
  for (int t = 0; t < 4; ++t) {
    float4 ub = ld4(Ueb + t * 16 + 4 * g);
    float4 vi = ld4(VXEP + ((size_t)((b * 16 + jti) * 4 + t)) * 256 + (g * 16 + r16i) * 4);
    uv[t][0] = ub.x + vi.x; uv[t][1] = ub.y + vi.y;
    uv[t][2] = ub.z + vi.z; uv[t][3] = ub.w + vi.w;
  }

  // prologue: prefetch A tiles 0,1
  float4 A0[4], A1[4];
  loadA(A0, eTile, w * 64 + 0 * 16, r16, g);
  loadA(A1, eTile, w * 64 + 1 * 16, r16, g);

  float sS[4][4] = {}, sQ[4][4] = {}, sA[4][4] = {};

#pragma unroll
  for (int p = 0; p < 4; ++p) {
    // packed epilogue loads for this phase (L2-resident; used ~after MFMA)
    const size_t pb = (size_t)((b * 16 + (w * 4 + p)) * 4);
    float4 vj4[4], vn4[4];
#pragma unroll
    for (int t = 0; t < 4; ++t) {
      vj4[t] = ld4(VXEP + (pb + t) * 256 + lane * 4);
      vn4[t] = ld4(VXNP + (pb + t) * 256 + lane * 4);
    }

    // consume prefetched A slot, then refill it for phase p+2
    float4* As = (p & 1) ? A1 : A0;
    bf16x8 aF0 = cvt8(As[0], As[1]);
    bf16x8 aF1 = cvt8(As[2], As[3]);
    if (p < 2) loadA(As, eTile, w * 64 + (p + 2) * 16, r16, g);

    f32x4 acc[4];
#pragma unroll
    for (int t = 0; t < 4; ++t) {
      f32x4 z = {0.f, 0.f, 0.f, 0.f};
      acc[t] = __builtin_amdgcn_mfma_f32_16x16x32_bf16(wF0[t], aF0, z, 0, 0, 0);
      acc[t] = __builtin_amdgcn_mfma_f32_16x16x32_bf16(wF1[t], aF1, acc[t], 0, 0, 0);
    }

#pragma unroll
    for (int t = 0; t < 4; ++t) {
      float vj[4] = {vj4[t].x, vj4[t].y, vj4[t].z, vj4[t].w};
      float vn[4] = {vn4[t].x, vn4[t].y, vn4[t].z, vn4[t].w};
#pragma unroll
      for (int r = 0; r < 4; ++r) {
        float tv = acc[t][r] + uv[t][r] + vj[r];
        sS[t][r] += tv;
        sQ[t][r]  = fmaf(tv, tv, sQ[t][r]);
        float sg  = __builtin_amdgcn_rcpf(1.0f + __expf(-tv));
        sA[t][r]  = fmaf(sg, vn[r], sA[t][r]);
      }
    }
  }

  // reduce over the 16 j-lanes (bits 0..3 of lane)
#pragma unroll
  for (int t = 0; t < 4; ++t)
#pragma unroll
    for (int r = 0; r < 4; ++r) {
#pragma unroll
      for (int m = 1; m < 16; m <<= 1) {
        sS[t][r] += __shfl_xor(sS[t][r], m);
        sQ[t][r] += __shfl_xor(sQ[t][r], m);
        sA[t][r] += __shfl_xor(sA[t][r], m);
      }
    }

  if (r16 == 0) {
#pragma unroll
    for (int t = 0; t < 4; ++t) {
      const int cb = w * 64 + t * 16 + 4 * g;
      *(float4*)(&redL[cb])       = make_float4(sA[t][0], sA[t][1], sA[t][2], sA[t][3]);
      *(float4*)(&redL[256 + cb]) = make_float4(sS[t][0], sS[t][1], sS[t][2], sS[t][3]);
      *(float4*)(&redL[512 + cb]) = make_float4(sQ[t][0], sQ[t][1], sQ[t][2], sQ[t][3]);
    }
  }
  __syncthreads();
  if (tid < 64) {
    const int c = tid;
    float a  = redL[c]       + redL[64 + c]        + redL[128 + c]       + redL[192 + c];
    ws[WS_AGG + (size_t)bi * 64 + c] = a;
    float s  = redL[256 + c] + redL[256 + 64 + c]  + redL[256 + 128 + c] + redL[256 + 192 + c];
    float qv = redL[512 + c] + redL[512 + 64 + c]  + redL[512 + 128 + c] + redL[512 + 192 + c];
    ws[WS_PART + (size_t)bi * 128 + c]      = s;     // no atomics
    ws[WS_PART + (size_t)bi * 128 + 64 + c] = qv;
  }
}

// ---------------------------------------------------------------------------
// Node path: reduce edge partials -> fold edge-BN scale/shift; then
// x_tmp = Ux + agg ; BN over (B,N) ; relu + residual.
__global__ __launch_bounds__(256) void k_node(
    const float* __restrict__ x,
    const float* __restrict__ bnng, const float* __restrict__ bnnb,
    const float* __restrict__ bneg, const float* __restrict__ bneb,
    float* __restrict__ ws, float* __restrict__ xOut)
{
  const int c = blockIdx.x;
  const int tid = threadIdx.x;
  __shared__ float ss[4], qq[4];
  const int w = tid >> 6;

  // ---- edge-BN stats from per-block partials
  float S = 0.f, Q = 0.f;
#pragma unroll
  for (int k = 0; k < 8; ++k) {
    const size_t row = (size_t)(tid + 256 * k) * 128;
    S += ws[WS_PART + row + c];
    Q += ws[WS_PART + row + 64 + c];
  }
#pragma unroll
  for (int m = 1; m < 64; m <<= 1) {
    S += __shfl_xor(S, m);
    Q += __shfl_xor(Q, m);
  }
  if ((tid & 63) == 0) { ss[w] = S; qq[w] = Q; }
  __syncthreads();
  if (tid == 0) {
    float Se = ss[0] + ss[1] + ss[2] + ss[3];
    float Qe = qq[0] + qq[1] + qq[2] + qq[3];
    float mean = Se * INV_EDGE_CNT;
    float var  = Qe * INV_EDGE_CNT - mean * mean;
    float sc = rsqrtf(var + EPSBN) * bneg[c];
    ws[WS_ESUM + c] = sc;
    ws[WS_ESQ  + c] = bneb[c] - mean * sc;
  }
  __syncthreads();   // ss/qq reuse below

  // ---- node path
  const float* Ux  = ws + WS_UX;
  const float* agg = ws + WS_AGG;

  float v[8];
  float s = 0.f, q = 0.f;
#pragma unroll
  for (int k = 0; k < 8; ++k) {
    int r = tid + 256 * k;
    float t = Ux[(size_t)r * 64 + c] + agg[(size_t)r * 64 + c];
    v[k] = t;
    s += t;
    q = fmaf(t, t, q);
  }
#pragma unroll
  for (int m = 1; m < 64; m <<= 1) {
    s += __shfl_xor(s, m);
    q += __shfl_xor(q, m);
  }
  if ((tid & 63) == 0) { ss[w] = s; qq[w] = q; }
  __syncthreads();
  float Sn = ss[0] + ss[1] + ss[2] + ss[3];
  float Qn = qq[0] + qq[1] + qq[2] + qq[3];
  float mean = Sn * INV_NODE_CNT;
  float var  = Qn * INV_NODE_CNT - mean * mean;
  float scv = rsqrtf(var + EPSBN) * bnng[c];
  float shv = bnnb[c] - mean * scv;
#pragma unroll
  for (int k = 0; k < 8; ++k) {
    int r = tid + 256 * k;
    float y = fmaf(v[k], scv, shv);
    xOut[(size_t)r * 64 + c] = fmaxf(y, 0.f) + x[(size_t)r * 64 + c];
  }
}

// ---------------------------------------------------------------------------
// Pass C: recompute e_tmp via MFMA (same LDS-free register pipeline), apply
// prefolded edge BN + relu + residual (residual direct global, L2-hot).
__global__ __launch_bounds__(256, 3) void k_edgeC(
    const float* __restrict__ e,
    const float* __restrict__ UeW, const float* __restrict__ Ueb,
    const float* __restrict__ ws, float* __restrict__ eOut)
{
  const int tid  = threadIdx.x;
  const int lane = tid & 63;
  const int w    = tid >> 6;
  const int bi   = blockIdx.x;
  const int b    = bi >> 8;
  const int r16  = lane & 15;
  const int g    = lane >> 4;

  const float* eTile = e + (size_t)bi * (Nv * Hv);
  float* oTile = eOut + (size_t)bi * (Nv * Hv);
  const float* VXEP = ws + WS_VXE;

  bf16x8 wF0[4], wF1[4];
#pragma unroll
  for (int t = 0; t < 4; ++t) {
    const float* wrow = UeW + (size_t)(t * 16 + r16) * 64 + 8 * g;
    wF0[t] = cvt8(ld4(wrow),      ld4(wrow + 4));
    wF1[t] = cvt8(ld4(wrow + 32), ld4(wrow + 36));
  }

  const int jti = (bi >> 4) & 15, r16i = bi & 15;
  float uv[4][4];
  float4 sc4[4], sh4[4];
#pragma unroll
  for (int t = 0; t < 4; ++t) {
    float4 ub = ld4(Ueb + t * 16 + 4 * g);
    float4 vi = ld4(VXEP + ((size_t)((b * 16 + jti) * 4 + t)) * 256 + (g * 16 + r16i) * 4);
    uv[t][0] = ub.x + vi.x; uv[t][1] = ub.y + vi.y;
    uv[t][2] = ub.z + vi.z; uv[t][3] = ub.w + vi.w;
    sc4[t] = ld4(ws + WS_ESUM + t * 16 + 4 * g);
    sh4[t] = ld4(ws + WS_ESQ  + t * 16 + 4 * g);
  }

  float4 A0[4], A1[4];
  loadA(A0, eTile, w * 64 + 0 * 16, r16, g);
  loadA(A1, eTile, w * 64 + 1 * 16, r16, g);

#pragma unroll
  for (int p = 0; p < 4; ++p) {
    const int j = w * 64 + p * 16 + r16;

    // epilogue data for this phase: Vxe_j (packed) + residual (direct)
    const size_t pb = (size_t)((b * 16 + (w * 4 + p)) * 4);
    float4 vj4[4], res4[4];
#pragma unroll
    for (int t = 0; t < 4; ++t) {
      vj4[t]  = ld4(VXEP + (pb + t) * 256 + lane * 4);
      res4[t] = ld4(eTile + (size_t)j * 64 + t * 16 + 4 * g);
    }

    float4* As = (p & 1) ? A1 : A0;
    bf16x8 aF0 = cvt8(As[0], As[1]);
    bf16x8 aF1 = cvt8(As[2], As[3]);
    if (p < 2) loadA(As, eTile, w * 64 + (p + 2) * 16, r16, g);

    f32x4 acc[4];
#pragma unroll
    for (int t = 0; t < 4; ++t) {
      f32x4 z = {0.f, 0.f, 0.f, 0.f};
      acc[t] = __builtin_amdgcn_mfma_f32_16x16x32_bf16(wF0[t], aF0, z, 0, 0, 0);
      acc[t] = __builtin_amdgcn_mfma_f32_16x16x32_bf16(wF1[t], aF1, acc[t], 0, 0, 0);
    }

#pragma unroll
    for (int t = 0; t < 4; ++t) {
      float vj[4] = {vj4[t].x, vj4[t].y, vj4[t].z, vj4[t].w};
      float rs[4] = {res4[t].x, res4[t].y, res4[t].z, res4[t].w};
      float sc[4] = {sc4[t].x, sc4[t].y, sc4[t].z, sc4[t].w};
      float sh[4] = {sh4[t].x, sh4[t].y, sh4[t].z, sh4[t].w};
      float out[4];
#pragma unroll
      for (int r = 0; r < 4; ++r) {
        float tv = acc[t][r] + uv[t][r] + vj[r];
        float y  = fmaf(tv, sc[r], sh[r]);
        out[r] = fmaxf(y, 0.f) + rs[r];
      }
      *(float4*)(oTile + (size_t)j * 64 + t * 16 + 4 * g) =
          make_float4(out[0], out[1], out[2], out[3]);
    }
  }
}

// ---------------------------------------------------------------------------
extern "C" void kernel_launch(void* const* d_in, const int* in_sizes, int n_in,
                              void* d_out, int out_size, void* d_ws, size_t ws_size,
                              hipStream_t stream)
{
  const float* x    = (const float*)d_in[0];
  const float* e    = (const float*)d_in[1];
  const float* UeW  = (const float*)d_in[2];
  const float* Ueb  = (const float*)d_in[3];
  const float* VeW  = (const float*)d_in[4];
  const float* Veb  = (const float*)d_in[5];
  const float* UnW  = (const float*)d_in[6];
  const float* Unb  = (const float*)d_in[7];
  const float* VnW  = (const float*)d_in[8];
  const float* Vnb  = (const float*)d_in[9];
  const float* bneg = (const float*)d_in[10];
  const float* bneb = (const float*)d_in[11];
  const float* bnng = (const float*)d_in[12];
  const float* bnnb = (const float*)d_in[13];

  float* ws   = (float*)d_ws;
  float* xOut = (float*)d_out;
  float* eOut = (float*)d_out + (size_t)ROWS * Hv;

  k_lin<<<128, 256, 0, stream>>>(x, VeW, Veb, UnW, Unb, VnW, Vnb, ws);
  k_edgeA<<<ROWS, 256, 0, stream>>>(e, UeW, Ueb, ws);
  k_node<<<Hv, 256, 0, stream>>>(x, bnng, bnnb, bneg, bneb, ws, xOut);
  k_edgeC<<<ROWS, 256, 0, stream>>>(e, UeW, Ueb, ws, eOut);
}